// Round 11
// baseline (587.667 us; speedup 1.0000x reference)
//
#include <hip/hip_runtime.h>
#include <hip/hip_bf16.h>
#include <stdint.h>

#define TSTEPS 4

typedef __bf16 bf16_t;
typedef __attribute__((ext_vector_type(8))) __bf16 bf16x8;
typedef __attribute__((ext_vector_type(16))) float f32x16;

union frag_u { bf16x8 v; unsigned short u[8]; };

// gfx9 s_waitcnt immediates: vmcnt low4 [3:0] hi2 [15:14]; expcnt=7,lgkm=15 off
#define VMCNT6  0xF76
#define VMCNT0  0xF70

// ---------------------------------------------------------------------------
// Fragment-order global layout ("A-frag"): packets of 1 KB:
//   packet p = blk32 * (K/16) + kblk16
//   within: lane*16B, lane = (row&31) + 32*((k>>3)&1), elem j = k&7
// Wave k-stream contiguous -> lane-linear global_load_dwordx4 -> MFMA regs.
// ---------------------------------------------------------------------------

// ---------------------------------------------------------------------------
// Stage 1: input LIF encoder -> spikes directly in A-frag layout. C=128.
// ---------------------------------------------------------------------------
__global__ void spike_encode_frag(const float* __restrict__ x,
                                  bf16_t* __restrict__ s1)
{
    const int M = 8192, C = 128;
    int gid = blockIdx.x * blockDim.x + threadIdx.x;   // 131072 total
    int lane = gid & 63;
    int packet = gid >> 6;                             // 2048 packets
    int m_blk = packet >> 3;
    int k_blk = packet & 7;
    int m = m_blk * 32 + (lane & 31);
    int c = k_blk * 16 + (lane >> 5) * 8;
    const float* px = x + (size_t)m * C + c;
    float4 x0 = *(const float4*)px;
    float4 x1 = *(const float4*)(px + 4);
    float xv[8] = {x0.x, x0.y, x0.z, x0.w, x1.x, x1.y, x1.z, x1.w};
    float v[8];
#pragma unroll
    for (int j = 0; j < 8; ++j) v[j] = 0.0f;
    size_t base = (size_t)packet * 512 + lane * 8;
#pragma unroll
    for (int t = 0; t < TSTEPS; ++t) {
        frag_u f;
#pragma unroll
        for (int j = 0; j < 8; ++j) {
            float vv = __fadd_rn(v[j], __fmul_rn(__fsub_rn(xv[j], v[j]), 0.5f));
            bool sp = (vv >= 1.0f);
            f.u[j] = sp ? 0x3F80 : 0;
            v[j] = sp ? 0.0f : vv;
        }
        *(bf16x8*)(s1 + (size_t)t * M * C + base) = f.v;
    }
}

// ---------------------------------------------------------------------------
// Weight prep: W [K][N] fp32 -> hi/lo bf16 split in B-frag layout.
// ---------------------------------------------------------------------------
__global__ void split_transpose_all(const float* __restrict__ enc_W,
                                    const float* __restrict__ W_cells,
                                    bf16_t* __restrict__ W1h, bf16_t* __restrict__ W1l,
                                    bf16_t* __restrict__ W2h, bf16_t* __restrict__ W2l,
                                    bf16_t* __restrict__ W3h, bf16_t* __restrict__ W3l)
{
    const int N = 1024;
    const float* W;
    bf16_t *hi, *lo;
    int K;
    if (blockIdx.z == 0) {
        if (blockIdx.x >= 4) return;
        W = enc_W; hi = W1h; lo = W1l; K = 128;
    } else if (blockIdx.z == 1) {
        W = W_cells; hi = W2h; lo = W2l; K = 1024;
    } else {
        W = W_cells + (size_t)1024 * 1024; hi = W3h; lo = W3l; K = 1024;
    }
    const int NKB = K >> 4;
    __shared__ float tile[32][33];
    int k0 = blockIdx.x * 32, n0 = blockIdx.y * 32;
    int tx = threadIdx.x & 31, ty = threadIdx.x >> 5;
    for (int kk = ty; kk < 32; kk += 8)
        tile[kk][tx] = W[(size_t)(k0 + kk) * N + n0 + tx];
    __syncthreads();
    for (int nn = ty; nn < 32; nn += 8) {
        float wv = tile[tx][nn];
        bf16_t h = (bf16_t)wv;
        bf16_t l = (bf16_t)(wv - (float)h);
        int n = n0 + nn, k = k0 + tx;
        size_t o = ((size_t)(n >> 5) * NKB + (k >> 4)) * 512
                 + (size_t)((n & 31) + ((k >> 3) & 1) * 32) * 8 + (k & 7);
        hi[o] = h;
        lo[o] = l;
    }
}

// ---------------------------------------------------------------------------
// Fused MFMA GEMM + multistep LIF.  R11 = R10 with ring-2 + 4 waves/SIMD.
// LDS-free K-loop; A/B in frag-order global layout. Block: 256 thr, 4 waves
// of 32x32 (2m x 2n) -> 64x64 tile; tau=4 (acc[4] f32x16 = 64 AGPR).
// Ring-2 register pipeline (12 frags = 48 VGPR) so VGPR+AGPR <= 128/wave ->
// 4 waves/SIMD: TLP covers memory latency (the R3..R10 plateau was 2 w/SIMD
// stalling in lockstep). Per kb: issue 6 loads for kb+1 -> vmcnt(6) [kb's
// landed, kb+1 in flight] -> 8 MFMAs (hi t0..t3, lo t0..t3; dependent-acc
// distance 4). Per-acc k-order unchanged -> bitwise-identical output.
// ---------------------------------------------------------------------------
template <int K, bool LAST>
__global__ __launch_bounds__(256, 4)
void gemm_lif_mfma(const bf16_t* __restrict__ Afrag,
                   const bf16_t* __restrict__ Bh,
                   const bf16_t* __restrict__ Bl,
                   const float* __restrict__ bias,
                   bf16_t* __restrict__ Sout,
                   float* __restrict__ Out,
                   int M, int N)
{
    constexpr int NKB = K >> 4;                 // 8 or 64 (even)
    __shared__ __align__(16) unsigned short sh[4][32 * 40];  // 10 KB, epilogue

    const int tid = threadIdx.x;
    const int lane = tid & 63;
    const int wid = tid >> 6;
    const int l31 = lane & 31;
    const int half = lane >> 5;

    // XCD swizzle (N=1024 -> 16 n-tiles, 2 per XCD; both n-tiles of one m
    // adjacent in dispatch -> A row L2-reused within XCD)
    int bid = blockIdx.x;
    int xcd = bid & 7, w = bid >> 3;
    const int n_t = (xcd << 1) | (w & 1);
    const int m_t = w >> 1;
    const int m0 = m_t * 64, n0 = n_t * 64;
    const int wave_m = (wid & 1) * 32;
    const int wave_n = (wid >> 1) * 32;
    const int m_blk = (m0 + wave_m) >> 5;
    const int n_blk = (n0 + wave_n) >> 5;

    const size_t tP = (size_t)M * K;            // elems per timestep plane
    const bf16_t* pA0 = Afrag + (size_t)m_blk * NKB * 512 + lane * 8;
    const bf16_t* pA1 = pA0 + tP;
    const bf16_t* pA2 = pA0 + 2 * tP;
    const bf16_t* pA3 = pA0 + 3 * tP;
    const bf16_t* pH = Bh + (size_t)n_blk * NKB * 512 + lane * 8;
    const bf16_t* pL = Bl + (size_t)n_blk * NKB * 512 + lane * 8;

    f32x16 acc[TSTEPS];
#pragma unroll
    for (int t = 0; t < TSTEPS; ++t)
        for (int rr = 0; rr < 16; ++rr) acc[t][rr] = 0.0f;

    bf16x8 fa[2][4], fh[2], fl[2];

#define LOADB(kb_, s_) {                                                     \
        const int _o = (kb_) * 512;                                          \
        fa[s_][0] = *(const bf16x8*)(pA0 + _o);                              \
        fa[s_][1] = *(const bf16x8*)(pA1 + _o);                              \
        fa[s_][2] = *(const bf16x8*)(pA2 + _o);                              \
        fa[s_][3] = *(const bf16x8*)(pA3 + _o);                              \
        fh[s_] = *(const bf16x8*)(pH + _o);                                  \
        fl[s_] = *(const bf16x8*)(pL + _o);                                  \
    }

#define MFMASTEP(s_) {                                                       \
        acc[0] = __builtin_amdgcn_mfma_f32_32x32x16_bf16(fa[s_][0], fh[s_], acc[0], 0, 0, 0); \
        acc[1] = __builtin_amdgcn_mfma_f32_32x32x16_bf16(fa[s_][1], fh[s_], acc[1], 0, 0, 0); \
        acc[2] = __builtin_amdgcn_mfma_f32_32x32x16_bf16(fa[s_][2], fh[s_], acc[2], 0, 0, 0); \
        acc[3] = __builtin_amdgcn_mfma_f32_32x32x16_bf16(fa[s_][3], fh[s_], acc[3], 0, 0, 0); \
        acc[0] = __builtin_amdgcn_mfma_f32_32x32x16_bf16(fa[s_][0], fl[s_], acc[0], 0, 0, 0); \
        acc[1] = __builtin_amdgcn_mfma_f32_32x32x16_bf16(fa[s_][1], fl[s_], acc[1], 0, 0, 0); \
        acc[2] = __builtin_amdgcn_mfma_f32_32x32x16_bf16(fa[s_][2], fl[s_], acc[2], 0, 0, 0); \
        acc[3] = __builtin_amdgcn_mfma_f32_32x32x16_bf16(fa[s_][3], fl[s_], acc[3], 0, 0, 0); \
    }

#define STEP(kb_, s_) {                                                      \
        if ((kb_) + 1 < NKB) {                                               \
            LOADB((kb_) + 1, (s_) ^ 1);                                      \
            __builtin_amdgcn_s_waitcnt(VMCNT6);                              \
        } else {                                                             \
            __builtin_amdgcn_s_waitcnt(VMCNT0);                              \
        }                                                                    \
        asm volatile("" ::: "memory");                                       \
        MFMASTEP(s_);                                                        \
    }

    LOADB(0, 0);
#pragma unroll 4
    for (int kb = 0; kb < NKB; kb += 2) {
        STEP(kb + 0, 0);
        STEP(kb + 1, 1);
    }

#undef STEP
#undef MFMASTEP
#undef LOADB

    // --- LIF epilogue: t-scan in registers (XLA-exact arithmetic) ---
    const float bv = bias[n0 + wave_n + l31];
    f32x16 vmem;
#pragma unroll
    for (int rr = 0; rr < 16; ++rr) vmem[rr] = 0.0f;
    uint64_t bits = 0ull;
    unsigned short* myt = &sh[wid][0];

    for (int t = 0; t < TSTEPS; ++t) {
        unsigned short spk[16];
#pragma unroll
        for (int rr = 0; rr < 16; ++rr) {
            float y = __fadd_rn(acc[t][rr], bv);
            float vv = vmem[rr];
            vv = __fadd_rn(vv, __fmul_rn(__fsub_rn(y, vv), 0.5f));
            bool sp = (vv >= 1.0f);
            vmem[rr] = sp ? 0.0f : vv;
            if (LAST) bits |= sp ? (1ull << (rr * 4 + t)) : 0ull;
            else spk[rr] = sp ? 0x3F80 : 0;
        }
        if (!LAST) {
#pragma unroll
            for (int rr = 0; rr < 16; ++rr) {
                int m_r = (rr & 3) + 8 * (rr >> 2) + 4 * half;
                myt[m_r * 40 + l31] = spk[rr];
            }
            __syncthreads();
#pragma unroll
            for (int kb2 = 0; kb2 < 2; ++kb2) {
                bf16x8 frag = *(const bf16x8*)&myt[l31 * 40 + kb2 * 16 + half * 8];
                size_t kg = (size_t)((n0 + wave_n) >> 4) + kb2;
                *(bf16x8*)(Sout + (size_t)t * M * N
                           + ((size_t)m_blk * (N >> 4) + kg) * 512 + lane * 8) = frag;
            }
            __syncthreads();
        }
    }

    if (LAST) {
#pragma unroll
        for (int rr = 0; rr < 16; ++rr) {
            int m_r = (rr & 3) + 8 * (rr >> 2) + 4 * half;
            int m = m0 + wave_m + m_r;
            int n = n0 + wave_n + l31;
            int cnt = __popc((unsigned)((bits >> (rr * 4)) & 0xFull));
            Out[(size_t)m * N + n] = 0.25f * (float)cnt;
        }
    }
}

// ---------------------------------------------------------------------------
// out2[b][d] = mean over L of out[b][l][d]. Exact in fp32 (quarter-integers).
// ---------------------------------------------------------------------------
__global__ void mean_over_L_kernel(const float* __restrict__ out,
                                   float* __restrict__ out2,
                                   int B, int L, int D)
{
    int id = blockIdx.x * blockDim.x + threadIdx.x;
    if (id >= B * D) return;
    int b = id / D, d = id - b * D;
    const float* p = out + (size_t)b * L * D + d;
    float s = 0.0f;
    for (int l = 0; l < L; ++l) s += p[(size_t)l * D];
    out2[id] = s * (1.0f / (float)L);
}

// ---------------------------------------------------------------------------
extern "C" void kernel_launch(void* const* d_in, const int* in_sizes, int n_in,
                              void* d_out, int out_size, void* d_ws, size_t ws_size,
                              hipStream_t stream)
{
    const float* inputs  = (const float*)d_in[0];  // [16,512,128]
    const float* enc_W   = (const float*)d_in[1];  // [128,1024]
    const float* enc_b   = (const float*)d_in[2];  // [1024]
    const float* W_cells = (const float*)d_in[3];  // [2,1024,1024]
    const float* b_cells = (const float*)d_in[4];  // [2,1024]

    const int B = 16, L = 512, C = 128, D = 1024;
    const int M = B * L;  // 8192

    // ws layout (all fragment-order): s1 8MB | W1h/l 0.5MB | W2h/l 4MB |
    // W3h/l 4MB | h0 64MB | h1 64MB
    char* ws = (char*)d_ws;
    size_t off = 0;
    bf16_t* s1 = (bf16_t*)(ws + off); off += (size_t)TSTEPS * M * C * 2;
    bf16_t* W1h = (bf16_t*)(ws + off); off += (size_t)C * D * 2;
    bf16_t* W1l = (bf16_t*)(ws + off); off += (size_t)C * D * 2;
    bf16_t* W2h = (bf16_t*)(ws + off); off += (size_t)D * D * 2;
    bf16_t* W2l = (bf16_t*)(ws + off); off += (size_t)D * D * 2;
    bf16_t* W3h = (bf16_t*)(ws + off); off += (size_t)D * D * 2;
    bf16_t* W3l = (bf16_t*)(ws + off); off += (size_t)D * D * 2;
    bf16_t* h0 = (bf16_t*)(ws + off); off += (size_t)TSTEPS * M * D * 2;
    bf16_t* h1 = (bf16_t*)(ws + off);

    float* out  = (float*)d_out;          // [M, D]
    float* out2 = out + (size_t)M * D;    // [B, D]

    split_transpose_all<<<dim3(32, 32, 3), 256, 0, stream>>>(
        enc_W, W_cells, W1h, W1l, W2h, W2l, W3h, W3l);

    spike_encode_frag<<<512, 256, 0, stream>>>(inputs, s1);

    const int nblocks = (M / 64) * (D / 64);   // 2048
    gemm_lif_mfma<128, false><<<nblocks, 256, 0, stream>>>(
        s1, W1h, W1l, enc_b, h0, nullptr, M, D);
    gemm_lif_mfma<1024, false><<<nblocks, 256, 0, stream>>>(
        h0, W2h, W2l, b_cells, h1, nullptr, M, D);
    gemm_lif_mfma<1024, true><<<nblocks, 256, 0, stream>>>(
        h1, W3h, W3l, b_cells + D, nullptr, out, M, D);

    mean_over_L_kernel<<<(B * D + 255) / 256, 256, 0, stream>>>(
        out, out2, B, L, D);
}

// Round 12
// 488.728 us; speedup vs baseline: 1.2024x; 1.2024x over previous
//
#include <hip/hip_runtime.h>
#include <hip/hip_bf16.h>
#include <stdint.h>

#define TSTEPS 4

typedef __bf16 bf16_t;
typedef __attribute__((ext_vector_type(8))) __bf16 bf16x8;
typedef __attribute__((ext_vector_type(16))) float f32x16;

union frag_u { bf16x8 v; unsigned short u[8]; };

// gfx9 s_waitcnt immediates: vmcnt low4 [3:0] hi2 [15:14]; expcnt=7,lgkm=15 off
#define VMCNT8  0xF78
#define VMCNT0  0xF70

// ---------------------------------------------------------------------------
// Fragment-order global layout ("A-frag"): packets of 1 KB:
//   packet p = blk32 * (K/16) + kblk16
//   within: lane*16B, lane = (row&31) + 32*((k>>3)&1), elem j = k&7
// Wave k-stream contiguous -> lane-linear global_load_dwordx4 -> MFMA regs.
// ---------------------------------------------------------------------------

// ---------------------------------------------------------------------------
// Stage 1: input LIF encoder -> spikes directly in A-frag layout. C=128.
// ---------------------------------------------------------------------------
__global__ void spike_encode_frag(const float* __restrict__ x,
                                  bf16_t* __restrict__ s1)
{
    const int M = 8192, C = 128;
    int gid = blockIdx.x * blockDim.x + threadIdx.x;   // 131072 total
    int lane = gid & 63;
    int packet = gid >> 6;                             // 2048 packets
    int m_blk = packet >> 3;
    int k_blk = packet & 7;
    int m = m_blk * 32 + (lane & 31);
    int c = k_blk * 16 + (lane >> 5) * 8;
    const float* px = x + (size_t)m * C + c;
    float4 x0 = *(const float4*)px;
    float4 x1 = *(const float4*)(px + 4);
    float xv[8] = {x0.x, x0.y, x0.z, x0.w, x1.x, x1.y, x1.z, x1.w};
    float v[8];
#pragma unroll
    for (int j = 0; j < 8; ++j) v[j] = 0.0f;
    size_t base = (size_t)packet * 512 + lane * 8;
#pragma unroll
    for (int t = 0; t < TSTEPS; ++t) {
        frag_u f;
#pragma unroll
        for (int j = 0; j < 8; ++j) {
            float vv = __fadd_rn(v[j], __fmul_rn(__fsub_rn(xv[j], v[j]), 0.5f));
            bool sp = (vv >= 1.0f);
            f.u[j] = sp ? 0x3F80 : 0;
            v[j] = sp ? 0.0f : vv;
        }
        *(bf16x8*)(s1 + (size_t)t * M * C + base) = f.v;
    }
}

// ---------------------------------------------------------------------------
// Weight prep: W [K][N] fp32 -> hi/lo bf16 split in B-frag layout.
// ---------------------------------------------------------------------------
__global__ void split_transpose_all(const float* __restrict__ enc_W,
                                    const float* __restrict__ W_cells,
                                    bf16_t* __restrict__ W1h, bf16_t* __restrict__ W1l,
                                    bf16_t* __restrict__ W2h, bf16_t* __restrict__ W2l,
                                    bf16_t* __restrict__ W3h, bf16_t* __restrict__ W3l)
{
    const int N = 1024;
    const float* W;
    bf16_t *hi, *lo;
    int K;
    if (blockIdx.z == 0) {
        if (blockIdx.x >= 4) return;
        W = enc_W; hi = W1h; lo = W1l; K = 128;
    } else if (blockIdx.z == 1) {
        W = W_cells; hi = W2h; lo = W2l; K = 1024;
    } else {
        W = W_cells + (size_t)1024 * 1024; hi = W3h; lo = W3l; K = 1024;
    }
    const int NKB = K >> 4;
    __shared__ float tile[32][33];
    int k0 = blockIdx.x * 32, n0 = blockIdx.y * 32;
    int tx = threadIdx.x & 31, ty = threadIdx.x >> 5;
    for (int kk = ty; kk < 32; kk += 8)
        tile[kk][tx] = W[(size_t)(k0 + kk) * N + n0 + tx];
    __syncthreads();
    for (int nn = ty; nn < 32; nn += 8) {
        float wv = tile[tx][nn];
        bf16_t h = (bf16_t)wv;
        bf16_t l = (bf16_t)(wv - (float)h);
        int n = n0 + nn, k = k0 + tx;
        size_t o = ((size_t)(n >> 5) * NKB + (k >> 4)) * 512
                 + (size_t)((n & 31) + ((k >> 3) & 1) * 32) * 8 + (k & 7);
        hi[o] = h;
        lo[o] = l;
    }
}

// ---------------------------------------------------------------------------
// Fused MFMA GEMM + multistep LIF.  R12: balanced wave tile 32m x 64n.
// LDS-free K-loop; A/B in frag-order global layout. Block: 256 thr = 4 waves
// (2m x 2n of 32x64) -> 64m x 128n tile; tau=4.
// acc[4t][2n] f32x16 = 128 AGPR; ring-2 frags (16 x 4 = 64 VGPR) -> ~218
// regs/wave, fits 2 waves/SIMD WITHOUT spill (R11's failure).
// Per kb: 8 loads (4A + 4B), 16 MFMAs -> 16 B/cyc demand == L1 supply
// (R10's 32x32 wave was 24 B/cyc -> <=67% ceiling, measured 41%).
// HBM locality: n_t = bid&7 -> one 128-wide n-tile per XCD (B 512 KB
// L2-pinned); m_t = bid>>3 -> all XCDs stream A in the same m-order (L3
// single hot window; R10 fetched A 4.3x from HBM).
// Per-acc hi->lo, ascending-kb order unchanged -> bitwise-identical output.
// ---------------------------------------------------------------------------
template <int K, bool LAST>
__global__ __launch_bounds__(256, 2)
void gemm_lif_mfma(const bf16_t* __restrict__ Afrag,
                   const bf16_t* __restrict__ Bh,
                   const bf16_t* __restrict__ Bl,
                   const float* __restrict__ bias,
                   bf16_t* __restrict__ Sout,
                   float* __restrict__ Out,
                   int M, int N)
{
    constexpr int NKB = K >> 4;                 // 8 or 64 (even)
    __shared__ __align__(16) unsigned short sh[4][32 * 40];  // 10 KB, epilogue

    const int tid = threadIdx.x;
    const int lane = tid & 63;
    const int wid = tid >> 6;
    const int l31 = lane & 31;
    const int half = lane >> 5;

    // n pinned per XCD, m streamed in same order on all XCDs
    int bid = blockIdx.x;
    const int n_t = bid & 7;                    // 8 n-tiles of 128
    const int m_t = bid >> 3;                   // 128 m-tiles of 64
    const int m0 = m_t * 64, n0 = n_t * 128;
    const int wave_m = (wid & 1) * 32;
    const int wave_n = (wid >> 1) * 64;
    const int m_blk = (m0 + wave_m) >> 5;
    const int n_blk = (n0 + wave_n) >> 5;       // and n_blk+1

    const size_t tP = (size_t)M * K;            // elems per timestep plane
    const bf16_t* pA0 = Afrag + (size_t)m_blk * NKB * 512 + lane * 8;
    const bf16_t* pA1 = pA0 + tP;
    const bf16_t* pA2 = pA0 + 2 * tP;
    const bf16_t* pA3 = pA0 + 3 * tP;
    const bf16_t* pH0 = Bh + (size_t)n_blk * NKB * 512 + lane * 8;
    const bf16_t* pH1 = Bh + (size_t)(n_blk + 1) * NKB * 512 + lane * 8;
    const bf16_t* pL0 = Bl + (size_t)n_blk * NKB * 512 + lane * 8;
    const bf16_t* pL1 = Bl + (size_t)(n_blk + 1) * NKB * 512 + lane * 8;

    f32x16 acc[TSTEPS][2];
#pragma unroll
    for (int t = 0; t < TSTEPS; ++t)
#pragma unroll
        for (int nb = 0; nb < 2; ++nb)
            for (int rr = 0; rr < 16; ++rr) acc[t][nb][rr] = 0.0f;

    bf16x8 fa[2][4], fb[2][4];                  // fb: H0,H1,L0,L1

#define LOADB(kb_, s_) {                                                     \
        const int _o = (kb_) * 512;                                          \
        fa[s_][0] = *(const bf16x8*)(pA0 + _o);                              \
        fa[s_][1] = *(const bf16x8*)(pA1 + _o);                              \
        fa[s_][2] = *(const bf16x8*)(pA2 + _o);                              \
        fa[s_][3] = *(const bf16x8*)(pA3 + _o);                              \
        fb[s_][0] = *(const bf16x8*)(pH0 + _o);                              \
        fb[s_][1] = *(const bf16x8*)(pH1 + _o);                              \
        fb[s_][2] = *(const bf16x8*)(pL0 + _o);                              \
        fb[s_][3] = *(const bf16x8*)(pL1 + _o);                              \
    }

// hi pass (8 independent accs), then lo pass: dependent-acc distance = 8.
// Per-acc sequence: hi@kb then lo@kb, kb ascending == R10 (bitwise match).
#define MFMASTEP(s_) {                                                       \
        acc[0][0] = __builtin_amdgcn_mfma_f32_32x32x16_bf16(fa[s_][0], fb[s_][0], acc[0][0], 0, 0, 0); \
        acc[1][0] = __builtin_amdgcn_mfma_f32_32x32x16_bf16(fa[s_][1], fb[s_][0], acc[1][0], 0, 0, 0); \
        acc[2][0] = __builtin_amdgcn_mfma_f32_32x32x16_bf16(fa[s_][2], fb[s_][0], acc[2][0], 0, 0, 0); \
        acc[3][0] = __builtin_amdgcn_mfma_f32_32x32x16_bf16(fa[s_][3], fb[s_][0], acc[3][0], 0, 0, 0); \
        acc[0][1] = __builtin_amdgcn_mfma_f32_32x32x16_bf16(fa[s_][0], fb[s_][1], acc[0][1], 0, 0, 0); \
        acc[1][1] = __builtin_amdgcn_mfma_f32_32x32x16_bf16(fa[s_][1], fb[s_][1], acc[1][1], 0, 0, 0); \
        acc[2][1] = __builtin_amdgcn_mfma_f32_32x32x16_bf16(fa[s_][2], fb[s_][1], acc[2][1], 0, 0, 0); \
        acc[3][1] = __builtin_amdgcn_mfma_f32_32x32x16_bf16(fa[s_][3], fb[s_][1], acc[3][1], 0, 0, 0); \
        acc[0][0] = __builtin_amdgcn_mfma_f32_32x32x16_bf16(fa[s_][0], fb[s_][2], acc[0][0], 0, 0, 0); \
        acc[1][0] = __builtin_amdgcn_mfma_f32_32x32x16_bf16(fa[s_][1], fb[s_][2], acc[1][0], 0, 0, 0); \
        acc[2][0] = __builtin_amdgcn_mfma_f32_32x32x16_bf16(fa[s_][2], fb[s_][2], acc[2][0], 0, 0, 0); \
        acc[3][0] = __builtin_amdgcn_mfma_f32_32x32x16_bf16(fa[s_][3], fb[s_][2], acc[3][0], 0, 0, 0); \
        acc[0][1] = __builtin_amdgcn_mfma_f32_32x32x16_bf16(fa[s_][0], fb[s_][3], acc[0][1], 0, 0, 0); \
        acc[1][1] = __builtin_amdgcn_mfma_f32_32x32x16_bf16(fa[s_][1], fb[s_][3], acc[1][1], 0, 0, 0); \
        acc[2][1] = __builtin_amdgcn_mfma_f32_32x32x16_bf16(fa[s_][2], fb[s_][3], acc[2][1], 0, 0, 0); \
        acc[3][1] = __builtin_amdgcn_mfma_f32_32x32x16_bf16(fa[s_][3], fb[s_][3], acc[3][1], 0, 0, 0); \
    }

#define STEP(kb_, s_) {                                                      \
        if ((kb_) + 1 < NKB) {                                               \
            LOADB((kb_) + 1, (s_) ^ 1);                                      \
            __builtin_amdgcn_s_waitcnt(VMCNT8);                              \
        } else {                                                             \
            __builtin_amdgcn_s_waitcnt(VMCNT0);                              \
        }                                                                    \
        asm volatile("" ::: "memory");                                       \
        MFMASTEP(s_);                                                        \
    }

    LOADB(0, 0);
#pragma unroll 2
    for (int kb = 0; kb < NKB; kb += 2) {
        STEP(kb + 0, 0);
        STEP(kb + 1, 1);
    }

#undef STEP
#undef MFMASTEP
#undef LOADB

    // --- LIF epilogue: t-scan in registers (XLA-exact arithmetic) ---
    float bv[2] = {bias[n0 + wave_n + l31], bias[n0 + wave_n + 32 + l31]};
    f32x16 vmem[2];
    uint64_t bits[2] = {0ull, 0ull};
#pragma unroll
    for (int nb = 0; nb < 2; ++nb)
        for (int rr = 0; rr < 16; ++rr) vmem[nb][rr] = 0.0f;
    unsigned short* myt = &sh[wid][0];

    for (int t = 0; t < TSTEPS; ++t) {
        for (int nb = 0; nb < 2; ++nb) {
            unsigned short spk[16];
#pragma unroll
            for (int rr = 0; rr < 16; ++rr) {
                float y = __fadd_rn(acc[t][nb][rr], bv[nb]);
                float vv = vmem[nb][rr];
                vv = __fadd_rn(vv, __fmul_rn(__fsub_rn(y, vv), 0.5f));
                bool sp = (vv >= 1.0f);
                vmem[nb][rr] = sp ? 0.0f : vv;
                if (LAST) bits[nb] |= sp ? (1ull << (rr * 4 + t)) : 0ull;
                else spk[rr] = sp ? 0x3F80 : 0;
            }
            if (!LAST) {
#pragma unroll
                for (int rr = 0; rr < 16; ++rr) {
                    int m_r = (rr & 3) + 8 * (rr >> 2) + 4 * half;
                    myt[m_r * 40 + l31] = spk[rr];
                }
                __syncthreads();
#pragma unroll
                for (int kb2 = 0; kb2 < 2; ++kb2) {
                    bf16x8 frag = *(const bf16x8*)&myt[l31 * 40 + kb2 * 16 + half * 8];
                    size_t kg = (size_t)((n0 + wave_n + nb * 32) >> 4) + kb2;
                    *(bf16x8*)(Sout + (size_t)t * M * N
                               + ((size_t)m_blk * (N >> 4) + kg) * 512 + lane * 8) = frag;
                }
                __syncthreads();
            }
        }
    }

    if (LAST) {
#pragma unroll
        for (int nb = 0; nb < 2; ++nb)
#pragma unroll
            for (int rr = 0; rr < 16; ++rr) {
                int m_r = (rr & 3) + 8 * (rr >> 2) + 4 * half;
                int m = m0 + wave_m + m_r;
                int n = n0 + wave_n + nb * 32 + l31;
                int cnt = __popc((unsigned)((bits[nb] >> (rr * 4)) & 0xFull));
                Out[(size_t)m * N + n] = 0.25f * (float)cnt;
            }
    }
}

// ---------------------------------------------------------------------------
// out2[b][d] = mean over L of out[b][l][d]. Exact in fp32 (quarter-integers).
// ---------------------------------------------------------------------------
__global__ void mean_over_L_kernel(const float* __restrict__ out,
                                   float* __restrict__ out2,
                                   int B, int L, int D)
{
    int id = blockIdx.x * blockDim.x + threadIdx.x;
    if (id >= B * D) return;
    int b = id / D, d = id - b * D;
    const float* p = out + (size_t)b * L * D + d;
    float s = 0.0f;
    for (int l = 0; l < L; ++l) s += p[(size_t)l * D];
    out2[id] = s * (1.0f / (float)L);
}

// ---------------------------------------------------------------------------
extern "C" void kernel_launch(void* const* d_in, const int* in_sizes, int n_in,
                              void* d_out, int out_size, void* d_ws, size_t ws_size,
                              hipStream_t stream)
{
    const float* inputs  = (const float*)d_in[0];  // [16,512,128]
    const float* enc_W   = (const float*)d_in[1];  // [128,1024]
    const float* enc_b   = (const float*)d_in[2];  // [1024]
    const float* W_cells = (const float*)d_in[3];  // [2,1024,1024]
    const float* b_cells = (const float*)d_in[4];  // [2,1024]

    const int B = 16, L = 512, C = 128, D = 1024;
    const int M = B * L;  // 8192

    // ws layout (all fragment-order): s1 8MB | W1h/l 0.5MB | W2h/l 4MB |
    // W3h/l 4MB | h0 64MB | h1 64MB
    char* ws = (char*)d_ws;
    size_t off = 0;
    bf16_t* s1 = (bf16_t*)(ws + off); off += (size_t)TSTEPS * M * C * 2;
    bf16_t* W1h = (bf16_t*)(ws + off); off += (size_t)C * D * 2;
    bf16_t* W1l = (bf16_t*)(ws + off); off += (size_t)C * D * 2;
    bf16_t* W2h = (bf16_t*)(ws + off); off += (size_t)D * D * 2;
    bf16_t* W2l = (bf16_t*)(ws + off); off += (size_t)D * D * 2;
    bf16_t* W3h = (bf16_t*)(ws + off); off += (size_t)D * D * 2;
    bf16_t* W3l = (bf16_t*)(ws + off); off += (size_t)D * D * 2;
    bf16_t* h0 = (bf16_t*)(ws + off); off += (size_t)TSTEPS * M * D * 2;
    bf16_t* h1 = (bf16_t*)(ws + off);

    float* out  = (float*)d_out;          // [M, D]
    float* out2 = out + (size_t)M * D;    // [B, D]

    split_transpose_all<<<dim3(32, 32, 3), 256, 0, stream>>>(
        enc_W, W_cells, W1h, W1l, W2h, W2l, W3h, W3l);

    spike_encode_frag<<<512, 256, 0, stream>>>(inputs, s1);

    const int nblocks = (M / 64) * (D / 128);   // 1024
    gemm_lif_mfma<128, false><<<nblocks, 256, 0, stream>>>(
        s1, W1h, W1l, enc_b, h0, nullptr, M, D);
    gemm_lif_mfma<1024, false><<<nblocks, 256, 0, stream>>>(
        h0, W2h, W2l, b_cells, h1, nullptr, M, D);
    gemm_lif_mfma<1024, true><<<nblocks, 256, 0, stream>>>(
        h1, W3h, W3l, b_cells + D, nullptr, out, M, D);

    mean_over_L_kernel<<<(B * D + 255) / 256, 256, 0, stream>>>(
        out, out2, B, L, D);
}